// Round 1
// baseline (957.725 us; speedup 1.0000x reference)
//
#include <hip/hip_runtime.h>
#include <math.h>

#define T_BINS 350
#define REF_LEN 32
#define NB 32
#define NPIX 3072
#define N1 240
#define N2 10
#define NVAL 256

// ---------------------------------------------------------------------------
// Kernel 1: per-batch CSR build — bucket pixel indices by pixel value,
// ascending pixel order within each bucket (deterministic).
// One block per batch image, 256 threads (one per pixel value).
// ---------------------------------------------------------------------------
__global__ void build_csr(const int* __restrict__ inp,
                          int* __restrict__ pix,    // [NB][NPIX]
                          int* __restrict__ offs,   // [NB][NVAL]
                          int* __restrict__ cnts)   // [NB][NVAL]
{
    __shared__ int li[NPIX];
    __shared__ int lc[NVAL];
    __shared__ int lo[NVAL];
    const int b = blockIdx.x;
    const int tid = threadIdx.x;

    for (int i = tid; i < NPIX; i += 256) li[i] = inp[b * NPIX + i];
    __syncthreads();

    const int v = tid;
    int c = 0;
    for (int p = 0; p < NPIX; ++p) c += (li[p] == v) ? 1 : 0;
    lc[v] = c;
    __syncthreads();

    if (tid == 0) {
        int acc = 0;
        for (int i = 0; i < NVAL; ++i) { lo[i] = acc; acc += lc[i]; }
    }
    __syncthreads();

    int o = lo[v];
    offs[b * NVAL + v] = o;
    cnts[b * NVAL + v] = lc[v];
    for (int p = 0; p < NPIX; ++p) {
        if (li[p] == v) { pix[b * NPIX + o] = p; ++o; }
    }
}

// ---------------------------------------------------------------------------
// Kernel 2: transpose w1 [240,3072] -> w1t [3072,240] so the u1 gather reads
// are coalesced across the n dimension.
// ---------------------------------------------------------------------------
__global__ void transpose_w1(const float* __restrict__ w1,
                             float* __restrict__ w1t)
{
    int id = blockIdx.x * 256 + threadIdx.x;   // id = p*N1 + n
    if (id >= NPIX * N1) return;
    int p = id / N1;
    int n = id - p * N1;
    w1t[id] = w1[n * NPIX + p];
}

// ---------------------------------------------------------------------------
// Kernel 3: u1[b, tbin(v), n] = sum over pixels with value v of w1[n, p].
// Grid = NB*NVAL blocks (b major), 256 threads (n = tid, guard n<240).
// fp64 accumulate, fixed ascending-pixel order -> deterministic & accurate.
// ---------------------------------------------------------------------------
__global__ void compute_u1(const float* __restrict__ w1t,
                           const int* __restrict__ table,
                           const int* __restrict__ pix,
                           const int* __restrict__ offs,
                           const int* __restrict__ cnts,
                           double* __restrict__ u1)   // [NB][T_BINS][N1]
{
    const int b = blockIdx.x >> 8;
    const int v = blockIdx.x & 255;
    const int n = threadIdx.x;
    if (n >= N1) return;

    const int cnt = cnts[b * NVAL + v];
    const int off = offs[b * NVAL + v];
    const int tb  = table[v];

    const int* pl = pix + b * NPIX + off;
    double acc = 0.0;
    for (int i = 0; i < cnt; ++i) {
        int p = pl[i];                      // wave-uniform broadcast load
        acc += (double)w1t[p * N1 + n];     // coalesced across threads
    }
    u1[((size_t)b * T_BINS + tb) * N1 + n] = acc;
}

// ---------------------------------------------------------------------------
// Kernel 4: layer-1 dynamics. One thread per (b,n) neuron: exact alpha-kernel
// IIR for PSP + 32-bit spike-history bitmask for the truncated refractory sum.
// Chunked loads (10 per chunk) so the serial loop isn't 1-load-latency/step.
// ---------------------------------------------------------------------------
__global__ void layer1_dyn(const double* __restrict__ u1,   // [NB][T][N1]
                           float* __restrict__ s1)          // [NB][T][N1]
{
    __shared__ double refk[REF_LEN];
    const int tid = threadIdx.x;
    if (tid < REF_LEN) refk[tid] = -20.0 * (double)tid * exp(1.0 - (double)tid);
    __syncthreads();

    const int id = blockIdx.x * 256 + tid;   // grid covers exactly NB*N1
    const int b = id / N1;
    const int n = id - b * N1;

    const double A = 0.9048374180359595;   // exp(-0.1)
    const double C = 0.2718281828459045;   // exp(1)/10

    double p = 0.0, q = 0.0;
    unsigned int hist = 0u;
    const double* up = u1 + (size_t)b * T_BINS * N1 + n;
    float*        sp = s1 + (size_t)b * T_BINS * N1 + n;

    for (int t0 = 0; t0 < T_BINS; t0 += 10) {
        double ub[10];
        #pragma unroll
        for (int i = 0; i < 10; ++i) ub[i] = up[(size_t)(t0 + i) * N1];
        #pragma unroll
        for (int i = 0; i < 10; ++i) {
            q = A * (q + p);
            p = A * p + ub[i];
            double y = C * q;
            double r = 0.0;
            unsigned int m = hist & 0xFFFFFFFEu;   // bit0 -> REF[0] == 0
            while (m) {
                int j = __ffs(m) - 1;
                r += refk[j];
                m &= m - 1;
            }
            unsigned int s = (y + r >= 10.0) ? 1u : 0u;
            hist = (hist << 1) | s;
            sp[(size_t)(t0 + i) * N1] = (float)s;
        }
    }
}

// ---------------------------------------------------------------------------
// Kernel 5: u2[b,t,m] = sum_n w2[m,n] * s1[b,t,n]  (fp64, fixed order)
// One thread per output element (112000 total).
// ---------------------------------------------------------------------------
__global__ void compute_u2(const float* __restrict__ s1,   // [NB][T][N1]
                           const float* __restrict__ w2,   // [N2][N1]
                           double* __restrict__ u2)        // [NB][T][N2]
{
    int id = blockIdx.x * 256 + threadIdx.x;
    if (id >= NB * T_BINS * N2) return;
    int bt = id / N2;
    int m  = id - bt * N2;
    const float* srow = s1 + (size_t)bt * N1;
    const float* wrow = w2 + m * N1;
    double acc = 0.0;
    #pragma unroll 8
    for (int n = 0; n < N1; ++n)
        acc += (double)srow[n] * (double)wrow[n];
    u2[id] = acc;
}

// ---------------------------------------------------------------------------
// Kernel 6: layer-2 dynamics. One thread per (b,m); writes final spikes.
// ---------------------------------------------------------------------------
__global__ void layer2_dyn(const double* __restrict__ u2,  // [NB][T][N2]
                           float* __restrict__ out)        // [NB][N2][T]
{
    __shared__ double refk[REF_LEN];
    const int tid = threadIdx.x;
    if (tid < REF_LEN) refk[tid] = -20.0 * (double)tid * exp(1.0 - (double)tid);
    __syncthreads();

    const int id = blockIdx.x * 64 + tid;
    if (id >= NB * N2) return;
    const int b = id / N2;
    const int m = id - b * N2;

    const double A = 0.9048374180359595;
    const double C = 0.2718281828459045;

    double p = 0.0, q = 0.0;
    unsigned int hist = 0u;
    const double* up = u2 + (size_t)b * T_BINS * N2 + m;
    float*        op = out + ((size_t)b * N2 + m) * T_BINS;

    for (int t0 = 0; t0 < T_BINS; t0 += 10) {
        double ub[10];
        #pragma unroll
        for (int i = 0; i < 10; ++i) ub[i] = up[(size_t)(t0 + i) * N2];
        #pragma unroll
        for (int i = 0; i < 10; ++i) {
            q = A * (q + p);
            p = A * p + ub[i];
            double y = C * q;
            double r = 0.0;
            unsigned int msk = hist & 0xFFFFFFFEu;
            while (msk) {
                int j = __ffs(msk) - 1;
                r += refk[j];
                msk &= msk - 1;
            }
            unsigned int s = (y + r >= 10.0) ? 1u : 0u;
            hist = (hist << 1) | s;
            op[t0 + i] = (float)s;
        }
    }
}

// ---------------------------------------------------------------------------
extern "C" void kernel_launch(void* const* d_in, const int* in_sizes, int n_in,
                              void* d_out, int out_size, void* d_ws, size_t ws_size,
                              hipStream_t stream) {
    const int*   inp   = (const int*)d_in[0];    // [32,3,32,32]
    const int*   table = (const int*)d_in[1];    // [256]
    const float* w1    = (const float*)d_in[2];  // [240,3072]
    const float* w2    = (const float*)d_in[3];  // [10,240]
    float* out = (float*)d_out;                  // [32,10,350]

    char* ws = (char*)d_ws;
    size_t off = 0;
    double* u1 = (double*)(ws + off); off += (size_t)NB * T_BINS * N1 * 8;  // 21.5 MB
    double* u2 = (double*)(ws + off); off += (size_t)NB * T_BINS * N2 * 8;  // 0.9 MB
    float* w1t = (float*)(ws + off);  off += (size_t)NPIX * N1 * 4;         // 2.9 MB
    float* s1  = (float*)(ws + off);  off += (size_t)NB * T_BINS * N1 * 4;  // 10.75 MB
    int*   pix = (int*)(ws + off);    off += (size_t)NB * NPIX * 4;
    int*  offs = (int*)(ws + off);    off += (size_t)NB * NVAL * 4;
    int*  cnts = (int*)(ws + off);    off += (size_t)NB * NVAL * 4;

    hipMemsetAsync(u1, 0, (size_t)NB * T_BINS * N1 * 8, stream);

    build_csr<<<NB, 256, 0, stream>>>(inp, pix, offs, cnts);
    transpose_w1<<<(NPIX * N1 + 255) / 256, 256, 0, stream>>>(w1, w1t);
    compute_u1<<<NB * NVAL, 256, 0, stream>>>(w1t, table, pix, offs, cnts, u1);
    layer1_dyn<<<(NB * N1) / 256, 256, 0, stream>>>(u1, s1);
    compute_u2<<<(NB * T_BINS * N2 + 255) / 256, 256, 0, stream>>>(s1, w2, u2);
    layer2_dyn<<<(NB * N2 + 63) / 64, 64, 0, stream>>>(u2, out);
}

// Round 2
// 361.714 us; speedup vs baseline: 2.6477x; 2.6477x over previous
//
#include <hip/hip_runtime.h>
#include <math.h>

#define T_BINS 350
#define REF_LEN 32
#define NB 32
#define NPIX 3072
#define N1 240
#define N2 10
#define NVAL 256

// ---------------------------------------------------------------------------
// Kernel 1: per-batch CSR build — bucket pixel indices by pixel value,
// ascending pixel order within each bucket (deterministic).
// ---------------------------------------------------------------------------
__global__ void build_csr(const int* __restrict__ inp,
                          int* __restrict__ pix,    // [NB][NPIX]
                          int* __restrict__ offs,   // [NB][NVAL]
                          int* __restrict__ cnts)   // [NB][NVAL]
{
    __shared__ int li[NPIX];
    __shared__ int lc[NVAL];
    __shared__ int lo[NVAL];
    const int b = blockIdx.x;
    const int tid = threadIdx.x;

    for (int i = tid; i < NPIX; i += 256) li[i] = inp[b * NPIX + i];
    __syncthreads();

    const int v = tid;
    int c = 0;
    for (int p = 0; p < NPIX; ++p) c += (li[p] == v) ? 1 : 0;
    lc[v] = c;
    __syncthreads();

    if (tid == 0) {
        int acc = 0;
        for (int i = 0; i < NVAL; ++i) { lo[i] = acc; acc += lc[i]; }
    }
    __syncthreads();

    int o = lo[v];
    offs[b * NVAL + v] = o;
    cnts[b * NVAL + v] = lc[v];
    for (int p = 0; p < NPIX; ++p) {
        if (li[p] == v) { pix[b * NPIX + o] = p; ++o; }
    }
}

// ---------------------------------------------------------------------------
// Kernel 2: transpose w1 [240,3072] -> w1t [3072,240] for coalesced gathers.
// ---------------------------------------------------------------------------
__global__ void transpose_w1(const float* __restrict__ w1,
                             float* __restrict__ w1t)
{
    int id = blockIdx.x * 256 + threadIdx.x;   // id = p*N1 + n
    if (id >= NPIX * N1) return;
    int p = id / N1;
    int n = id - p * N1;
    w1t[id] = w1[n * NPIX + p];
}

// ---------------------------------------------------------------------------
// Kernel 3: u1[b, tbin(v), n] = sum over pixels with value v of w1[n, p].
// ---------------------------------------------------------------------------
__global__ void compute_u1(const float* __restrict__ w1t,
                           const int* __restrict__ table,
                           const int* __restrict__ pix,
                           const int* __restrict__ offs,
                           const int* __restrict__ cnts,
                           double* __restrict__ u1)   // [NB][T_BINS][N1]
{
    const int b = blockIdx.x >> 8;
    const int v = blockIdx.x & 255;
    const int n = threadIdx.x;
    if (n >= N1) return;

    const int cnt = cnts[b * NVAL + v];
    const int off = offs[b * NVAL + v];
    const int tb  = table[v];

    const int* pl = pix + b * NPIX + off;
    double acc = 0.0;
    for (int i = 0; i < cnt; ++i) {
        int p = pl[i];                      // wave-uniform broadcast load
        acc += (double)w1t[p * N1 + n];     // coalesced across threads
    }
    u1[((size_t)b * T_BINS + tb) * N1 + n] = acc;
}

// ---------------------------------------------------------------------------
// Shared dynamics core: exact alpha-kernel IIR for PSP (A=e^-0.1) and an
// exact 2-state IIR for the TRUNCATED 32-tap refractory sum (Ar=e^-1) with
// expiry corrections driven by bits 30/31 of the spike-history mask.
//   r_t = -20e * Q_t,  Q_{t+1}=Ar*(Q_t+P_t - bit31*31e^-31),
//   P_{t+1}=s_t + Ar*P_t - bit30*e^-31
// No LDS, no inner loop: ~10 register fp64 ops/step.
// ---------------------------------------------------------------------------
__device__ __forceinline__ void run_dyn(const double* __restrict__ up, int ustride,
                                        float* __restrict__ sp, int sstride)
{
    const double A    = 0.9048374180359595;    // exp(-0.1)
    const double C    = 0.2718281828459045;    // exp(1)/10
    const double Ar   = 0.36787944117144233;   // exp(-1)
    const double Cr   = -54.365636569180904;   // -20*e
    const double C31A = 1.0671679036256927e-12; // 31*exp(-31)
    const double C31B = 3.4424771084699765e-14; // exp(-31)

    double p = 0.0, q = 0.0, P = 0.0, Q = 0.0;
    unsigned int hist = 0u;

    double cb[10], nb[10];
    #pragma unroll
    for (int i = 0; i < 10; ++i) cb[i] = up[(size_t)i * ustride];

    for (int t0 = 0; t0 < T_BINS; t0 += 10) {
        if (t0 + 10 < T_BINS) {
            #pragma unroll
            for (int i = 0; i < 10; ++i) nb[i] = up[(size_t)(t0 + 10 + i) * ustride];
        }
        #pragma unroll
        for (int i = 0; i < 10; ++i) {
            q = A * (q + p);
            p = A * p + cb[i];
            double v = C * q + Cr * Q;              // y + refractory
            unsigned int sb = (v >= 10.0) ? 1u : 0u;
            double s = (double)sb;
            double sel31 = (hist & 0x80000000u) ? C31A : 0.0;
            double sel30 = (hist & 0x40000000u) ? C31B : 0.0;
            Q = Ar * (Q + P - sel31);               // uses OLD P
            P = s + (Ar * P - sel30);
            hist = (hist << 1) | sb;
            sp[(size_t)(t0 + i) * sstride] = (float)s;
        }
        #pragma unroll
        for (int i = 0; i < 10; ++i) cb[i] = nb[i];
    }
}

// ---------------------------------------------------------------------------
// Kernel 4: layer-1 dynamics, one thread per (b,n).
// ---------------------------------------------------------------------------
__global__ void layer1_dyn(const double* __restrict__ u1,   // [NB][T][N1]
                           float* __restrict__ s1)          // [NB][T][N1]
{
    const int id = blockIdx.x * 256 + threadIdx.x;   // exactly NB*N1 threads
    const int b = id / N1;
    const int n = id - b * N1;
    run_dyn(u1 + (size_t)b * T_BINS * N1 + n, N1,
            s1 + (size_t)b * T_BINS * N1 + n, N1);
}

// ---------------------------------------------------------------------------
// Kernel 5: u2[b,t,m] = sum_n w2[m,n] * s1[b,t,n]  (fp64, fixed order)
// ---------------------------------------------------------------------------
__global__ void compute_u2(const float* __restrict__ s1,   // [NB][T][N1]
                           const float* __restrict__ w2,   // [N2][N1]
                           double* __restrict__ u2)        // [NB][T][N2]
{
    int id = blockIdx.x * 256 + threadIdx.x;
    if (id >= NB * T_BINS * N2) return;
    int bt = id / N2;
    int m  = id - bt * N2;
    const float* srow = s1 + (size_t)bt * N1;
    const float* wrow = w2 + m * N1;
    double acc = 0.0;
    #pragma unroll 8
    for (int n = 0; n < N1; ++n)
        acc += (double)srow[n] * (double)wrow[n];
    u2[id] = acc;
}

// ---------------------------------------------------------------------------
// Kernel 6: layer-2 dynamics, one thread per (b,m); writes final spikes
// in [B][N2][T] layout.
// ---------------------------------------------------------------------------
__global__ void layer2_dyn(const double* __restrict__ u2,  // [NB][T][N2]
                           float* __restrict__ out)        // [NB][N2][T]
{
    const int id = blockIdx.x * 64 + threadIdx.x;
    if (id >= NB * N2) return;
    const int b = id / N2;
    const int m = id - b * N2;
    run_dyn(u2 + (size_t)b * T_BINS * N2 + m, N2,
            out + ((size_t)b * N2 + m) * T_BINS, 1);
}

// ---------------------------------------------------------------------------
extern "C" void kernel_launch(void* const* d_in, const int* in_sizes, int n_in,
                              void* d_out, int out_size, void* d_ws, size_t ws_size,
                              hipStream_t stream) {
    const int*   inp   = (const int*)d_in[0];    // [32,3,32,32]
    const int*   table = (const int*)d_in[1];    // [256]
    const float* w1    = (const float*)d_in[2];  // [240,3072]
    const float* w2    = (const float*)d_in[3];  // [10,240]
    float* out = (float*)d_out;                  // [32,10,350]

    char* ws = (char*)d_ws;
    size_t off = 0;
    double* u1 = (double*)(ws + off); off += (size_t)NB * T_BINS * N1 * 8;  // 21.5 MB
    double* u2 = (double*)(ws + off); off += (size_t)NB * T_BINS * N2 * 8;  // 0.9 MB
    float* w1t = (float*)(ws + off);  off += (size_t)NPIX * N1 * 4;         // 2.9 MB
    float* s1  = (float*)(ws + off);  off += (size_t)NB * T_BINS * N1 * 4;  // 10.75 MB
    int*   pix = (int*)(ws + off);    off += (size_t)NB * NPIX * 4;
    int*  offs = (int*)(ws + off);    off += (size_t)NB * NVAL * 4;
    int*  cnts = (int*)(ws + off);    off += (size_t)NB * NVAL * 4;

    hipMemsetAsync(u1, 0, (size_t)NB * T_BINS * N1 * 8, stream);

    build_csr<<<NB, 256, 0, stream>>>(inp, pix, offs, cnts);
    transpose_w1<<<(NPIX * N1 + 255) / 256, 256, 0, stream>>>(w1, w1t);
    compute_u1<<<NB * NVAL, 256, 0, stream>>>(w1t, table, pix, offs, cnts, u1);
    layer1_dyn<<<(NB * N1) / 256, 256, 0, stream>>>(u1, s1);
    compute_u2<<<(NB * T_BINS * N2 + 255) / 256, 256, 0, stream>>>(s1, w2, u2);
    layer2_dyn<<<(NB * N2 + 63) / 64, 64, 0, stream>>>(u2, out);
}

// Round 3
// 174.984 us; speedup vs baseline: 5.4732x; 2.0671x over previous
//
#include <hip/hip_runtime.h>
#include <math.h>

#define T_BINS 350
#define REF_LEN 32
#define NB 32
#define NPIX 3072
#define N1 240
#define N2 10
#define NVAL 256

// ---------------------------------------------------------------------------
// Kernel 1: per-batch CSR build — histogram (LDS atomics) + Hillis-Steele
// exclusive scan + atomic-slot scatter. Order within a bucket is arbitrary
// (only perturbs fp64 bucket sums at ~1e-13, far below spike margins).
// One block per batch image, 256 threads; 12 pixels/thread, coalesced loads.
// ---------------------------------------------------------------------------
__global__ void build_csr(const int* __restrict__ inp,
                          int* __restrict__ pix,    // [NB][NPIX]
                          int* __restrict__ offs,   // [NB][NVAL]
                          int* __restrict__ cnts)   // [NB][NVAL]
{
    __shared__ int lc[NVAL];     // histogram
    __shared__ int ls[NVAL];     // scan workspace
    __shared__ int lslot[NVAL];  // running slot counters
    const int b = blockIdx.x;
    const int tid = threadIdx.x;

    lc[tid] = 0;
    __syncthreads();

    int vals[12];
    #pragma unroll
    for (int i = 0; i < 12; ++i) {
        int v = inp[b * NPIX + i * 256 + tid];   // coalesced
        vals[i] = v;
        atomicAdd(&lc[v], 1);
    }
    __syncthreads();

    // inclusive scan in ls (Hillis-Steele, double-barrier)
    int x = lc[tid];
    ls[tid] = x;
    __syncthreads();
    for (int d = 1; d < 256; d <<= 1) {
        int y = (tid >= d) ? ls[tid - d] : 0;
        __syncthreads();
        ls[tid] += y;
        __syncthreads();
    }
    int excl = ls[tid] - x;
    offs[b * NVAL + tid] = excl;
    cnts[b * NVAL + tid] = x;
    lslot[tid] = excl;
    __syncthreads();

    #pragma unroll
    for (int i = 0; i < 12; ++i) {
        int slot = atomicAdd(&lslot[vals[i]], 1);
        pix[b * NPIX + slot] = i * 256 + tid;
    }
}

// ---------------------------------------------------------------------------
// Kernel 2: tiled transpose w1 [240,3072] -> w1t [3072,240].
// 64x64 tiles, coalesced load and store; LDS pad 65 -> conflict-free.
// Grid dim3(48, 4): 48 tiles along p, 4 along n (last partial, 48 rows).
// ---------------------------------------------------------------------------
__global__ void transpose_w1(const float* __restrict__ w1,
                             float* __restrict__ w1t)
{
    __shared__ float tile[64][65];
    const int c  = threadIdx.x & 63;
    const int r0 = threadIdx.x >> 6;     // 0..3
    const int p0 = blockIdx.x * 64;
    const int n0 = blockIdx.y * 64;

    #pragma unroll
    for (int i = 0; i < 16; ++i) {
        int n = n0 + r0 + i * 4;
        if (n < N1) tile[r0 + i * 4][c] = w1[n * NPIX + p0 + c];
    }
    __syncthreads();
    #pragma unroll
    for (int i = 0; i < 16; ++i) {
        int p = p0 + r0 + i * 4;
        int n = n0 + c;
        if (n < N1) w1t[p * N1 + n] = tile[c][r0 + i * 4];
    }
}

// ---------------------------------------------------------------------------
// Kernel 3: u1[b, tbin(v), n] = sum over pixels with value v of w1t[p, n].
// ---------------------------------------------------------------------------
__global__ void compute_u1(const float* __restrict__ w1t,
                           const int* __restrict__ table,
                           const int* __restrict__ pix,
                           const int* __restrict__ offs,
                           const int* __restrict__ cnts,
                           double* __restrict__ u1)   // [NB][T_BINS][N1]
{
    const int b = blockIdx.x >> 8;
    const int v = blockIdx.x & 255;
    const int n = threadIdx.x;
    if (n >= N1) return;

    const int cnt = cnts[b * NVAL + v];
    const int off = offs[b * NVAL + v];
    const int tb  = table[v];

    const int* pl = pix + b * NPIX + off;
    double acc = 0.0;
    for (int i = 0; i < cnt; ++i) {
        int p = pl[i];                      // wave-uniform broadcast load
        acc += (double)w1t[p * N1 + n];     // coalesced across threads
    }
    u1[((size_t)b * T_BINS + tb) * N1 + n] = acc;
}

// ---------------------------------------------------------------------------
// Shared dynamics core: exact alpha-kernel IIR for PSP (A=e^-0.1) and an
// exact 2-state IIR for the TRUNCATED 32-tap refractory sum (Ar=e^-1) with
// expiry corrections driven by bits 30/31 of the spike-history mask.
// ---------------------------------------------------------------------------
__device__ __forceinline__ void run_dyn(const double* __restrict__ up, int ustride,
                                        float* __restrict__ sp, int sstride)
{
    const double A    = 0.9048374180359595;    // exp(-0.1)
    const double C    = 0.2718281828459045;    // exp(1)/10
    const double Ar   = 0.36787944117144233;   // exp(-1)
    const double Cr   = -54.365636569180904;   // -20*e
    const double C31A = 1.0671679036256927e-12; // 31*exp(-31)
    const double C31B = 3.4424771084699765e-14; // exp(-31)

    double p = 0.0, q = 0.0, P = 0.0, Q = 0.0;
    unsigned int hist = 0u;

    double cb[10], nb[10];
    #pragma unroll
    for (int i = 0; i < 10; ++i) cb[i] = up[(size_t)i * ustride];

    for (int t0 = 0; t0 < T_BINS; t0 += 10) {
        if (t0 + 10 < T_BINS) {
            #pragma unroll
            for (int i = 0; i < 10; ++i) nb[i] = up[(size_t)(t0 + 10 + i) * ustride];
        }
        #pragma unroll
        for (int i = 0; i < 10; ++i) {
            q = A * (q + p);
            p = A * p + cb[i];
            double v = C * q + Cr * Q;              // y + refractory
            unsigned int sb = (v >= 10.0) ? 1u : 0u;
            double s = (double)sb;
            double sel31 = (hist & 0x80000000u) ? C31A : 0.0;
            double sel30 = (hist & 0x40000000u) ? C31B : 0.0;
            Q = Ar * (Q + P - sel31);               // uses OLD P
            P = s + (Ar * P - sel30);
            hist = (hist << 1) | sb;
            sp[(size_t)(t0 + i) * sstride] = (float)s;
        }
        #pragma unroll
        for (int i = 0; i < 10; ++i) cb[i] = nb[i];
    }
}

// ---------------------------------------------------------------------------
// Kernel 4: layer-1 dynamics, one thread per (b,n).
// ---------------------------------------------------------------------------
__global__ void layer1_dyn(const double* __restrict__ u1,   // [NB][T][N1]
                           float* __restrict__ s1)          // [NB][T][N1]
{
    const int id = blockIdx.x * 256 + threadIdx.x;   // exactly NB*N1 threads
    const int b = id / N1;
    const int n = id - b * N1;
    run_dyn(u1 + (size_t)b * T_BINS * N1 + n, N1,
            s1 + (size_t)b * T_BINS * N1 + n, N1);
}

// ---------------------------------------------------------------------------
// Kernel 5: u2[b,t,m] = sum_n w2[m,n] * s1[b,t,n]  (fp64, fixed order)
// ---------------------------------------------------------------------------
__global__ void compute_u2(const float* __restrict__ s1,   // [NB][T][N1]
                           const float* __restrict__ w2,   // [N2][N1]
                           double* __restrict__ u2)        // [NB][T][N2]
{
    int id = blockIdx.x * 256 + threadIdx.x;
    if (id >= NB * T_BINS * N2) return;
    int bt = id / N2;
    int m  = id - bt * N2;
    const float* srow = s1 + (size_t)bt * N1;
    const float* wrow = w2 + m * N1;
    double acc = 0.0;
    #pragma unroll 8
    for (int n = 0; n < N1; ++n)
        acc += (double)srow[n] * (double)wrow[n];
    u2[id] = acc;
}

// ---------------------------------------------------------------------------
// Kernel 6: layer-2 dynamics, one thread per (b,m); writes [B][N2][T].
// ---------------------------------------------------------------------------
__global__ void layer2_dyn(const double* __restrict__ u2,  // [NB][T][N2]
                           float* __restrict__ out)        // [NB][N2][T]
{
    const int id = blockIdx.x * 64 + threadIdx.x;
    if (id >= NB * N2) return;
    const int b = id / N2;
    const int m = id - b * N2;
    run_dyn(u2 + (size_t)b * T_BINS * N2 + m, N2,
            out + ((size_t)b * N2 + m) * T_BINS, 1);
}

// ---------------------------------------------------------------------------
extern "C" void kernel_launch(void* const* d_in, const int* in_sizes, int n_in,
                              void* d_out, int out_size, void* d_ws, size_t ws_size,
                              hipStream_t stream) {
    const int*   inp   = (const int*)d_in[0];    // [32,3,32,32]
    const int*   table = (const int*)d_in[1];    // [256]
    const float* w1    = (const float*)d_in[2];  // [240,3072]
    const float* w2    = (const float*)d_in[3];  // [10,240]
    float* out = (float*)d_out;                  // [32,10,350]

    char* ws = (char*)d_ws;
    size_t off = 0;
    double* u1 = (double*)(ws + off); off += (size_t)NB * T_BINS * N1 * 8;  // 21.5 MB
    double* u2 = (double*)(ws + off); off += (size_t)NB * T_BINS * N2 * 8;  // 0.9 MB
    float* w1t = (float*)(ws + off);  off += (size_t)NPIX * N1 * 4;         // 2.9 MB
    float* s1  = (float*)(ws + off);  off += (size_t)NB * T_BINS * N1 * 4;  // 10.75 MB
    int*   pix = (int*)(ws + off);    off += (size_t)NB * NPIX * 4;
    int*  offs = (int*)(ws + off);    off += (size_t)NB * NVAL * 4;
    int*  cnts = (int*)(ws + off);    off += (size_t)NB * NVAL * 4;

    hipMemsetAsync(u1, 0, (size_t)NB * T_BINS * N1 * 8, stream);

    build_csr<<<NB, 256, 0, stream>>>(inp, pix, offs, cnts);
    transpose_w1<<<dim3(48, 4), 256, 0, stream>>>(w1, w1t);
    compute_u1<<<NB * NVAL, 256, 0, stream>>>(w1t, table, pix, offs, cnts, u1);
    layer1_dyn<<<(NB * N1) / 256, 256, 0, stream>>>(u1, s1);
    compute_u2<<<(NB * T_BINS * N2 + 255) / 256, 256, 0, stream>>>(s1, w2, u2);
    layer2_dyn<<<(NB * N2 + 63) / 64, 64, 0, stream>>>(u2, out);
}

// Round 4
// 171.063 us; speedup vs baseline: 5.5987x; 1.0229x over previous
//
#include <hip/hip_runtime.h>
#include <math.h>

#define T_BINS 350
#define REF_LEN 32
#define NB 32
#define NPIX 3072
#define N1 240
#define N2 10
#define NVAL 256

// ---------------------------------------------------------------------------
// Kernel 1 (fused): blocks 0..31 -> per-batch CSR build (histogram + scan +
// atomic-slot scatter); blocks 32..223 -> 64x64 tiled transpose of w1.
// ---------------------------------------------------------------------------
__global__ void prep(const int* __restrict__ inp,
                     int* __restrict__ pix,    // [NB][NPIX]
                     int* __restrict__ offs,   // [NB][NVAL]
                     int* __restrict__ cnts,   // [NB][NVAL]
                     const float* __restrict__ w1,
                     float* __restrict__ w1t)
{
    __shared__ int lc[NVAL];
    __shared__ int ls[NVAL];
    __shared__ int lslot[NVAL];
    __shared__ float tile[64][65];

    const int tid = threadIdx.x;

    if (blockIdx.x < NB) {
        // ---- CSR build for batch b ----
        const int b = blockIdx.x;
        lc[tid] = 0;
        __syncthreads();

        int vals[12];
        #pragma unroll
        for (int i = 0; i < 12; ++i) {
            int v = inp[b * NPIX + i * 256 + tid];   // coalesced
            vals[i] = v;
            atomicAdd(&lc[v], 1);
        }
        __syncthreads();

        int x = lc[tid];
        ls[tid] = x;
        __syncthreads();
        for (int d = 1; d < 256; d <<= 1) {
            int y = (tid >= d) ? ls[tid - d] : 0;
            __syncthreads();
            ls[tid] += y;
            __syncthreads();
        }
        int excl = ls[tid] - x;
        offs[b * NVAL + tid] = excl;
        cnts[b * NVAL + tid] = x;
        lslot[tid] = excl;
        __syncthreads();

        #pragma unroll
        for (int i = 0; i < 12; ++i) {
            int slot = atomicAdd(&lslot[vals[i]], 1);
            pix[b * NPIX + slot] = i * 256 + tid;
        }
    } else {
        // ---- transpose tile ----
        const int tt = blockIdx.x - NB;       // 0..191
        const int p0 = (tt % 48) * 64;
        const int n0 = (tt / 48) * 64;
        const int c  = tid & 63;
        const int r0 = tid >> 6;              // 0..3

        #pragma unroll
        for (int i = 0; i < 16; ++i) {
            int n = n0 + r0 + i * 4;
            if (n < N1) tile[r0 + i * 4][c] = w1[n * NPIX + p0 + c];
        }
        __syncthreads();
        #pragma unroll
        for (int i = 0; i < 16; ++i) {
            int p = p0 + r0 + i * 4;
            int n = n0 + c;
            if (n < N1) w1t[p * N1 + n] = tile[c][r0 + i * 4];
        }
    }
}

// ---------------------------------------------------------------------------
// Kernel 2: u1v[b][v][n] = sum over pixels with value v of w1t[p, n].
// DENSE over v (zero written when bucket empty) -> no memset needed.
// Pixel list staged through LDS to break the dependent-load chain.
// ---------------------------------------------------------------------------
__global__ void compute_u1(const float* __restrict__ w1t,
                           const int* __restrict__ pix,
                           const int* __restrict__ offs,
                           const int* __restrict__ cnts,
                           double* __restrict__ u1v)  // [NB][NVAL][N1]
{
    __shared__ int lpix[NPIX];   // worst case whole image one value
    const int b = blockIdx.x >> 8;
    const int v = blockIdx.x & 255;
    const int tid = threadIdx.x;

    const int cnt = cnts[b * NVAL + v];
    const int off = offs[b * NVAL + v];
    const int* pl = pix + b * NPIX + off;

    for (int i = tid; i < cnt; i += 256) lpix[i] = pl[i];
    __syncthreads();

    if (tid >= N1) return;
    double acc = 0.0;
    for (int i = 0; i < cnt; ++i)
        acc += (double)w1t[lpix[i] * N1 + tid];     // coalesced across threads
    u1v[((size_t)b * NVAL + v) * N1 + tid] = acc;
}

// ---------------------------------------------------------------------------
// Dynamics math (shared by both layers):
//   PSP alpha-kernel exact IIR:  q=A(q+p); p=Ap+u; y=(e/10)q   A=e^-0.1
//   Truncated 32-tap refractory exact IIR with expiry corrections from
//   bits 30/31 of the spike-history mask:
//     r=-20e*Q;  Q'=e^-1(Q+P-bit31*31e^-31);  P'=s+e^-1 P-bit30*e^-31
// ---------------------------------------------------------------------------
#define DYN_CONSTS \
    const double A    = 0.9048374180359595;     \
    const double C    = 0.2718281828459045;     \
    const double Ar   = 0.36787944117144233;    \
    const double Cr   = -54.365636569180904;    \
    const double C31A = 1.0671679036256927e-12; \
    const double C31B = 3.4424771084699765e-14;

#define DYN_STEP(uin, sout)                                   \
    {                                                         \
        q = A * (q + p);                                      \
        p = A * p + (uin);                                    \
        double vm = C * q + Cr * Q;                           \
        unsigned int sb = (vm >= 10.0) ? 1u : 0u;             \
        double s = (double)sb;                                \
        double sel31 = (hist & 0x80000000u) ? C31A : 0.0;     \
        double sel30 = (hist & 0x40000000u) ? C31B : 0.0;     \
        Q = Ar * (Q + P - sel31);                             \
        P = s + (Ar * P - sel30);                             \
        hist = (hist << 1) | sb;                              \
        (sout) = (float)s;                                    \
    }

// ---------------------------------------------------------------------------
// Kernel 3: layer-1 dynamics. One block per batch b, thread n.
// u comes from dense u1v via LDS inverse map bin->value (-1 if empty).
// ---------------------------------------------------------------------------
__global__ void layer1_dyn(const double* __restrict__ u1v,  // [NB][NVAL][N1]
                           const int* __restrict__ table,   // [NVAL]
                           float* __restrict__ s1)          // [NB][T][N1]
{
    __shared__ int linv[T_BINS];
    const int tid = threadIdx.x;
    const int b = blockIdx.x;

    for (int i = tid; i < T_BINS; i += 256) linv[i] = -1;
    __syncthreads();
    if (tid < NVAL) linv[table[tid]] = tid;
    __syncthreads();

    if (tid >= N1) return;
    const double* ub = u1v + (size_t)b * NVAL * N1 + tid;
    float*        sp = s1 + (size_t)b * T_BINS * N1 + tid;

    DYN_CONSTS
    double p = 0.0, q = 0.0, P = 0.0, Q = 0.0;
    unsigned int hist = 0u;

    double cb[10], nb[10];
    #pragma unroll
    for (int i = 0; i < 10; ++i) {
        int iv = linv[i];
        cb[i] = (iv >= 0) ? ub[(size_t)iv * N1] : 0.0;
    }

    for (int t0 = 0; t0 < T_BINS; t0 += 10) {
        if (t0 + 10 < T_BINS) {
            #pragma unroll
            for (int i = 0; i < 10; ++i) {
                int iv = linv[t0 + 10 + i];
                nb[i] = (iv >= 0) ? ub[(size_t)iv * N1] : 0.0;
            }
        }
        #pragma unroll
        for (int i = 0; i < 10; ++i)
            DYN_STEP(cb[i], sp[(size_t)(t0 + i) * N1]);
        #pragma unroll
        for (int i = 0; i < 10; ++i) cb[i] = nb[i];
    }
}

// ---------------------------------------------------------------------------
// Kernel 4: u2[b,t,m] = sum_n w2[m,n] * s1[b,t,n]  — float4 loads, fp64 acc.
// ---------------------------------------------------------------------------
__global__ void compute_u2(const float* __restrict__ s1,   // [NB][T][N1]
                           const float* __restrict__ w2,   // [N2][N1]
                           double* __restrict__ u2)        // [NB][T][N2]
{
    int id = blockIdx.x * 256 + threadIdx.x;
    if (id >= NB * T_BINS * N2) return;
    int bt = id / N2;
    int m  = id - bt * N2;
    const float4* s4 = (const float4*)(s1 + (size_t)bt * N1);
    const float4* w4 = (const float4*)(w2 + m * N1);
    double a0 = 0.0, a1 = 0.0;
    #pragma unroll 4
    for (int i = 0; i < N1 / 4; ++i) {
        float4 sv = s4[i];
        float4 wv = w4[i];
        a0 += (double)sv.x * (double)wv.x + (double)sv.y * (double)wv.y;
        a1 += (double)sv.z * (double)wv.z + (double)sv.w * (double)wv.w;
    }
    u2[id] = a0 + a1;
}

// ---------------------------------------------------------------------------
// Kernel 5: layer-2 dynamics, one thread per (b,m); writes [B][N2][T].
// ---------------------------------------------------------------------------
__global__ void layer2_dyn(const double* __restrict__ u2,  // [NB][T][N2]
                           float* __restrict__ out)        // [NB][N2][T]
{
    const int id = blockIdx.x * 64 + threadIdx.x;
    if (id >= NB * N2) return;
    const int b = id / N2;
    const int m = id - b * N2;
    const double* up = u2 + (size_t)b * T_BINS * N2 + m;
    float*        op = out + ((size_t)b * N2 + m) * T_BINS;

    DYN_CONSTS
    double p = 0.0, q = 0.0, P = 0.0, Q = 0.0;
    unsigned int hist = 0u;

    double cb[10], nb[10];
    #pragma unroll
    for (int i = 0; i < 10; ++i) cb[i] = up[(size_t)i * N2];

    for (int t0 = 0; t0 < T_BINS; t0 += 10) {
        if (t0 + 10 < T_BINS) {
            #pragma unroll
            for (int i = 0; i < 10; ++i) nb[i] = up[(size_t)(t0 + 10 + i) * N2];
        }
        #pragma unroll
        for (int i = 0; i < 10; ++i)
            DYN_STEP(cb[i], op[t0 + i]);
        #pragma unroll
        for (int i = 0; i < 10; ++i) cb[i] = nb[i];
    }
}

// ---------------------------------------------------------------------------
extern "C" void kernel_launch(void* const* d_in, const int* in_sizes, int n_in,
                              void* d_out, int out_size, void* d_ws, size_t ws_size,
                              hipStream_t stream) {
    const int*   inp   = (const int*)d_in[0];    // [32,3,32,32]
    const int*   table = (const int*)d_in[1];    // [256]
    const float* w1    = (const float*)d_in[2];  // [240,3072]
    const float* w2    = (const float*)d_in[3];  // [10,240]
    float* out = (float*)d_out;                  // [32,10,350]

    char* ws = (char*)d_ws;
    size_t off = 0;
    double* u1v = (double*)(ws + off); off += (size_t)NB * NVAL * N1 * 8;   // 15.7 MB
    double* u2  = (double*)(ws + off); off += (size_t)NB * T_BINS * N2 * 8; // 0.9 MB
    float* w1t  = (float*)(ws + off);  off += (size_t)NPIX * N1 * 4;        // 2.9 MB
    float* s1   = (float*)(ws + off);  off += (size_t)NB * T_BINS * N1 * 4; // 10.75 MB
    int*   pix  = (int*)(ws + off);    off += (size_t)NB * NPIX * 4;
    int*  offs  = (int*)(ws + off);    off += (size_t)NB * NVAL * 4;
    int*  cnts  = (int*)(ws + off);    off += (size_t)NB * NVAL * 4;

    prep<<<NB + 192, 256, 0, stream>>>(inp, pix, offs, cnts, w1, w1t);
    compute_u1<<<NB * NVAL, 256, 0, stream>>>(w1t, pix, offs, cnts, u1v);
    layer1_dyn<<<NB, 256, 0, stream>>>(u1v, table, s1);
    compute_u2<<<(NB * T_BINS * N2 + 255) / 256, 256, 0, stream>>>(s1, w2, u2);
    layer2_dyn<<<(NB * N2 + 63) / 64, 64, 0, stream>>>(u2, out);
}

// Round 5
// 166.627 us; speedup vs baseline: 5.7477x; 1.0266x over previous
//
#include <hip/hip_runtime.h>
#include <math.h>

#define T_BINS 350
#define REF_LEN 32
#define NB 32
#define NPIX 3072
#define N1 240
#define N2 10
#define NVAL 256

// ---------------------------------------------------------------------------
// Kernel 1 (fused): blocks 0..31 -> per-batch CSR build (histogram + scan +
// atomic-slot scatter); blocks 32..223 -> 64x64 tiled transpose of w1.
// ---------------------------------------------------------------------------
__global__ void prep(const int* __restrict__ inp,
                     int* __restrict__ pix,    // [NB][NPIX]
                     int* __restrict__ offs,   // [NB][NVAL]
                     int* __restrict__ cnts,   // [NB][NVAL]
                     const float* __restrict__ w1,
                     float* __restrict__ w1t)
{
    __shared__ int lc[NVAL];
    __shared__ int ls[NVAL];
    __shared__ int lslot[NVAL];
    __shared__ float tile[64][65];

    const int tid = threadIdx.x;

    if (blockIdx.x < NB) {
        // ---- CSR build for batch b ----
        const int b = blockIdx.x;
        lc[tid] = 0;
        __syncthreads();

        int vals[12];
        #pragma unroll
        for (int i = 0; i < 12; ++i) {
            int v = inp[b * NPIX + i * 256 + tid];   // coalesced
            vals[i] = v;
            atomicAdd(&lc[v], 1);
        }
        __syncthreads();

        int x = lc[tid];
        ls[tid] = x;
        __syncthreads();
        for (int d = 1; d < 256; d <<= 1) {
            int y = (tid >= d) ? ls[tid - d] : 0;
            __syncthreads();
            ls[tid] += y;
            __syncthreads();
        }
        int excl = ls[tid] - x;
        offs[b * NVAL + tid] = excl;
        cnts[b * NVAL + tid] = x;
        lslot[tid] = excl;
        __syncthreads();

        #pragma unroll
        for (int i = 0; i < 12; ++i) {
            int slot = atomicAdd(&lslot[vals[i]], 1);
            pix[b * NPIX + slot] = i * 256 + tid;
        }
    } else {
        // ---- transpose tile ----
        const int tt = blockIdx.x - NB;       // 0..191
        const int p0 = (tt % 48) * 64;
        const int n0 = (tt / 48) * 64;
        const int c  = tid & 63;
        const int r0 = tid >> 6;              // 0..3

        #pragma unroll
        for (int i = 0; i < 16; ++i) {
            int n = n0 + r0 + i * 4;
            if (n < N1) tile[r0 + i * 4][c] = w1[n * NPIX + p0 + c];
        }
        __syncthreads();
        #pragma unroll
        for (int i = 0; i < 16; ++i) {
            int p = p0 + r0 + i * 4;
            int n = n0 + c;
            if (n < N1) w1t[p * N1 + n] = tile[c][r0 + i * 4];
        }
    }
}

// ---------------------------------------------------------------------------
// Kernel 2: u1v[b][v][n] = sum over pixels with value v of w1t[p, n].
// DENSE over v (zero written when bucket empty) -> no memset needed.
// ---------------------------------------------------------------------------
__global__ void compute_u1(const float* __restrict__ w1t,
                           const int* __restrict__ pix,
                           const int* __restrict__ offs,
                           const int* __restrict__ cnts,
                           double* __restrict__ u1v)  // [NB][NVAL][N1]
{
    __shared__ int lpix[NPIX];   // worst case whole image one value
    const int b = blockIdx.x >> 8;
    const int v = blockIdx.x & 255;
    const int tid = threadIdx.x;

    const int cnt = cnts[b * NVAL + v];
    const int off = offs[b * NVAL + v];
    const int* pl = pix + b * NPIX + off;

    for (int i = tid; i < cnt; i += 256) lpix[i] = pl[i];
    __syncthreads();

    if (tid >= N1) return;
    double acc = 0.0;
    for (int i = 0; i < cnt; ++i)
        acc += (double)w1t[lpix[i] * N1 + tid];     // coalesced across threads
    u1v[((size_t)b * NVAL + v) * N1 + tid] = acc;
}

// ---------------------------------------------------------------------------
// Dynamics math (shared by both layers):
//   PSP alpha-kernel exact IIR:  q=A(q+p); p=Ap+u; y=(e/10)q   A=e^-0.1
//   Truncated 32-tap refractory exact IIR with expiry corrections from
//   bits 30/31 of the spike-history mask:
//     r=-20e*Q;  Q'=e^-1(Q+P-bit31*31e^-31);  P'=s+e^-1 P-bit30*e^-31
// ---------------------------------------------------------------------------
#define DYN_CONSTS \
    const double A    = 0.9048374180359595;     \
    const double C    = 0.2718281828459045;     \
    const double Ar   = 0.36787944117144233;    \
    const double Cr   = -54.365636569180904;    \
    const double C31A = 1.0671679036256927e-12; \
    const double C31B = 3.4424771084699765e-14;

#define DYN_STEP(uin, sout)                                   \
    {                                                         \
        q = A * (q + p);                                      \
        p = A * p + (uin);                                    \
        double vm = C * q + Cr * Q;                           \
        unsigned int sb = (vm >= 10.0) ? 1u : 0u;             \
        double s = (double)sb;                                \
        double sel31 = (hist & 0x80000000u) ? C31A : 0.0;     \
        double sel30 = (hist & 0x40000000u) ? C31B : 0.0;     \
        Q = Ar * (Q + P - sel31);                             \
        P = s + (Ar * P - sel30);                             \
        hist = (hist << 1) | sb;                              \
        (sout) = (float)s;                                    \
    }

// ---------------------------------------------------------------------------
// Kernel 3: layer-1 dynamics. 128 blocks x 64 threads: block -> (b, n-group),
// one wave per block so up to 128 CUs stream u1v (per-CU BW was the R4 limit).
// u comes from dense u1v via LDS inverse map bin->value (-1 if empty).
// ---------------------------------------------------------------------------
__global__ __launch_bounds__(64) void layer1_dyn(
                           const double* __restrict__ u1v,  // [NB][NVAL][N1]
                           const int* __restrict__ table,   // [NVAL]
                           float* __restrict__ s1)          // [NB][T][N1]
{
    __shared__ int linv[T_BINS];
    const int tid = threadIdx.x;             // 0..63
    const int b   = blockIdx.x >> 2;
    const int n   = (blockIdx.x & 3) * 64 + tid;

    for (int i = tid; i < T_BINS; i += 64) linv[i] = -1;
    __syncthreads();
    for (int i = tid; i < NVAL; i += 64) linv[table[i]] = i;  // injective table
    __syncthreads();

    if (n >= N1) return;
    const double* ub = u1v + (size_t)b * NVAL * N1 + n;
    float*        sp = s1 + (size_t)b * T_BINS * N1 + n;

    DYN_CONSTS
    double p = 0.0, q = 0.0, P = 0.0, Q = 0.0;
    unsigned int hist = 0u;

    double cb[10], nb[10];
    #pragma unroll
    for (int i = 0; i < 10; ++i) {
        int iv = linv[i];
        cb[i] = (iv >= 0) ? ub[(size_t)iv * N1] : 0.0;
    }

    for (int t0 = 0; t0 < T_BINS; t0 += 10) {
        if (t0 + 10 < T_BINS) {
            #pragma unroll
            for (int i = 0; i < 10; ++i) {
                int iv = linv[t0 + 10 + i];
                nb[i] = (iv >= 0) ? ub[(size_t)iv * N1] : 0.0;
            }
        }
        #pragma unroll
        for (int i = 0; i < 10; ++i)
            DYN_STEP(cb[i], sp[(size_t)(t0 + i) * N1]);
        #pragma unroll
        for (int i = 0; i < 10; ++i) cb[i] = nb[i];
    }
}

// ---------------------------------------------------------------------------
// Kernel 4: u2[b,t,m] = sum_n w2[m,n] * s1[b,t,n]  — float4 loads, fp64 acc.
// ---------------------------------------------------------------------------
__global__ void compute_u2(const float* __restrict__ s1,   // [NB][T][N1]
                           const float* __restrict__ w2,   // [N2][N1]
                           double* __restrict__ u2)        // [NB][T][N2]
{
    int id = blockIdx.x * 256 + threadIdx.x;
    if (id >= NB * T_BINS * N2) return;
    int bt = id / N2;
    int m  = id - bt * N2;
    const float4* s4 = (const float4*)(s1 + (size_t)bt * N1);
    const float4* w4 = (const float4*)(w2 + m * N1);
    double a0 = 0.0, a1 = 0.0;
    #pragma unroll 4
    for (int i = 0; i < N1 / 4; ++i) {
        float4 sv = s4[i];
        float4 wv = w4[i];
        a0 += (double)sv.x * (double)wv.x + (double)sv.y * (double)wv.y;
        a1 += (double)sv.z * (double)wv.z + (double)sv.w * (double)wv.w;
    }
    u2[id] = a0 + a1;
}

// ---------------------------------------------------------------------------
// Kernel 5: layer-2 dynamics, one thread per (b,m); writes [B][N2][T].
// 14-deep prefetch chunks (25 load-waits instead of 35 on the serial chain).
// ---------------------------------------------------------------------------
__global__ void layer2_dyn(const double* __restrict__ u2,  // [NB][T][N2]
                           float* __restrict__ out)        // [NB][N2][T]
{
    const int id = blockIdx.x * 64 + threadIdx.x;
    if (id >= NB * N2) return;
    const int b = id / N2;
    const int m = id - b * N2;
    const double* up = u2 + (size_t)b * T_BINS * N2 + m;
    float*        op = out + ((size_t)b * N2 + m) * T_BINS;

    DYN_CONSTS
    double p = 0.0, q = 0.0, P = 0.0, Q = 0.0;
    unsigned int hist = 0u;

    double cb[14], nb[14];
    #pragma unroll
    for (int i = 0; i < 14; ++i) cb[i] = up[(size_t)i * N2];

    for (int t0 = 0; t0 < T_BINS; t0 += 14) {
        if (t0 + 14 < T_BINS) {
            #pragma unroll
            for (int i = 0; i < 14; ++i) nb[i] = up[(size_t)(t0 + 14 + i) * N2];
        }
        #pragma unroll
        for (int i = 0; i < 14; ++i)
            DYN_STEP(cb[i], op[t0 + i]);
        #pragma unroll
        for (int i = 0; i < 14; ++i) cb[i] = nb[i];
    }
}

// ---------------------------------------------------------------------------
extern "C" void kernel_launch(void* const* d_in, const int* in_sizes, int n_in,
                              void* d_out, int out_size, void* d_ws, size_t ws_size,
                              hipStream_t stream) {
    const int*   inp   = (const int*)d_in[0];    // [32,3,32,32]
    const int*   table = (const int*)d_in[1];    // [256]
    const float* w1    = (const float*)d_in[2];  // [240,3072]
    const float* w2    = (const float*)d_in[3];  // [10,240]
    float* out = (float*)d_out;                  // [32,10,350]

    char* ws = (char*)d_ws;
    size_t off = 0;
    double* u1v = (double*)(ws + off); off += (size_t)NB * NVAL * N1 * 8;   // 15.7 MB
    double* u2  = (double*)(ws + off); off += (size_t)NB * T_BINS * N2 * 8; // 0.9 MB
    float* w1t  = (float*)(ws + off);  off += (size_t)NPIX * N1 * 4;        // 2.9 MB
    float* s1   = (float*)(ws + off);  off += (size_t)NB * T_BINS * N1 * 4; // 10.75 MB
    int*   pix  = (int*)(ws + off);    off += (size_t)NB * NPIX * 4;
    int*  offs  = (int*)(ws + off);    off += (size_t)NB * NVAL * 4;
    int*  cnts  = (int*)(ws + off);    off += (size_t)NB * NVAL * 4;

    prep<<<NB + 192, 256, 0, stream>>>(inp, pix, offs, cnts, w1, w1t);
    compute_u1<<<NB * NVAL, 256, 0, stream>>>(w1t, pix, offs, cnts, u1v);
    layer1_dyn<<<NB * 4, 64, 0, stream>>>(u1v, table, s1);
    compute_u2<<<(NB * T_BINS * N2 + 255) / 256, 256, 0, stream>>>(s1, w2, u2);
    layer2_dyn<<<(NB * N2 + 63) / 64, 64, 0, stream>>>(u2, out);
}

// Round 6
// 155.605 us; speedup vs baseline: 6.1549x; 1.0708x over previous
//
#include <hip/hip_runtime.h>
#include <math.h>

#define T_BINS 350
#define REF_LEN 32
#define NB 32
#define NPIX 3072
#define N1 240
#define N2 10
#define NVAL 256

// ---------------------------------------------------------------------------
// Kernel 1 (fused): blocks 0..31 -> per-batch CSR build; blocks 32..223 ->
// 64x64 tiled transpose of w1; block 224 -> inverse bin map inv[t]=v or -1.
// ---------------------------------------------------------------------------
__global__ void prep(const int* __restrict__ inp,
                     int* __restrict__ pix,    // [NB][NPIX]
                     int* __restrict__ offs,   // [NB][NVAL]
                     int* __restrict__ cnts,   // [NB][NVAL]
                     const float* __restrict__ w1,
                     float* __restrict__ w1t,
                     const int* __restrict__ table,
                     int* __restrict__ inv)    // [T_BINS]
{
    __shared__ int lc[NVAL];
    __shared__ int ls[NVAL];
    __shared__ int lslot[NVAL];
    __shared__ float tile[64][65];
    __shared__ int linv[T_BINS];

    const int tid = threadIdx.x;

    if (blockIdx.x < NB) {
        // ---- CSR build for batch b ----
        const int b = blockIdx.x;
        lc[tid] = 0;
        __syncthreads();

        int vals[12];
        #pragma unroll
        for (int i = 0; i < 12; ++i) {
            int v = inp[b * NPIX + i * 256 + tid];   // coalesced
            vals[i] = v;
            atomicAdd(&lc[v], 1);
        }
        __syncthreads();

        int x = lc[tid];
        ls[tid] = x;
        __syncthreads();
        for (int d = 1; d < 256; d <<= 1) {
            int y = (tid >= d) ? ls[tid - d] : 0;
            __syncthreads();
            ls[tid] += y;
            __syncthreads();
        }
        int excl = ls[tid] - x;
        offs[b * NVAL + tid] = excl;
        cnts[b * NVAL + tid] = x;
        lslot[tid] = excl;
        __syncthreads();

        #pragma unroll
        for (int i = 0; i < 12; ++i) {
            int slot = atomicAdd(&lslot[vals[i]], 1);
            pix[b * NPIX + slot] = i * 256 + tid;
        }
    } else if (blockIdx.x < NB + 192) {
        // ---- transpose tile ----
        const int tt = blockIdx.x - NB;       // 0..191
        const int p0 = (tt % 48) * 64;
        const int n0 = (tt / 48) * 64;
        const int c  = tid & 63;
        const int r0 = tid >> 6;              // 0..3

        #pragma unroll
        for (int i = 0; i < 16; ++i) {
            int n = n0 + r0 + i * 4;
            if (n < N1) tile[r0 + i * 4][c] = w1[n * NPIX + p0 + c];
        }
        __syncthreads();
        #pragma unroll
        for (int i = 0; i < 16; ++i) {
            int p = p0 + r0 + i * 4;
            int n = n0 + c;
            if (n < N1) w1t[p * N1 + n] = tile[c][r0 + i * 4];
        }
    } else {
        // ---- inverse bin map (table is injective value->bin) ----
        for (int i = tid; i < T_BINS; i += 256) linv[i] = -1;
        __syncthreads();
        if (tid < NVAL) linv[table[tid]] = tid;
        __syncthreads();
        for (int i = tid; i < T_BINS; i += 256) inv[i] = linv[i];
    }
}

// ---------------------------------------------------------------------------
// Kernel 2: u1t[b][t][n] = sum over pixels with value inv[t] of w1t[p, n];
// zero when bin t is empty. DENSE in t -> layer1_dyn streams with no
// indirection. Gather order identical to previous rounds (bit-identical u1).
// Grid: dim3(T_BINS, NB), 256 threads.
// ---------------------------------------------------------------------------
__global__ void compute_u1(const float* __restrict__ w1t,
                           const int* __restrict__ pix,
                           const int* __restrict__ offs,
                           const int* __restrict__ cnts,
                           const int* __restrict__ inv,
                           double* __restrict__ u1t)  // [NB][T_BINS][N1]
{
    __shared__ int lpix[NPIX];
    const int t = blockIdx.x;
    const int b = blockIdx.y;
    const int tid = threadIdx.x;
    const int v = inv[t];                    // block-uniform

    double acc = 0.0;
    if (v >= 0) {
        const int cnt = cnts[b * NVAL + v];
        const int off = offs[b * NVAL + v];
        const int* pl = pix + b * NPIX + off;
        for (int i = tid; i < cnt; i += 256) lpix[i] = pl[i];
        __syncthreads();
        if (tid < N1)
            for (int i = 0; i < cnt; ++i)
                acc += (double)w1t[lpix[i] * N1 + tid];   // coalesced
    }
    if (tid < N1)
        u1t[((size_t)b * T_BINS + t) * N1 + tid] = acc;
}

// ---------------------------------------------------------------------------
// Dynamics math (shared by both layers):
//   PSP alpha-kernel exact IIR:  q=A(q+p); p=Ap+u; y=(e/10)q   A=e^-0.1
//   Truncated 32-tap refractory exact IIR with expiry corrections from
//   bits 30/31 of the spike-history mask:
//     r=-20e*Q;  Q'=e^-1(Q+P-bit31*31e^-31);  P'=s+e^-1 P-bit30*e^-31
// ---------------------------------------------------------------------------
#define DYN_CONSTS \
    const double A    = 0.9048374180359595;     \
    const double C    = 0.2718281828459045;     \
    const double Ar   = 0.36787944117144233;    \
    const double Cr   = -54.365636569180904;    \
    const double C31A = 1.0671679036256927e-12; \
    const double C31B = 3.4424771084699765e-14;

#define DYN_STEP(uin, sout)                                   \
    {                                                         \
        q = A * (q + p);                                      \
        p = A * p + (uin);                                    \
        double vm = C * q + Cr * Q;                           \
        unsigned int sb = (vm >= 10.0) ? 1u : 0u;             \
        double s = (double)sb;                                \
        double sel31 = (hist & 0x80000000u) ? C31A : 0.0;     \
        double sel30 = (hist & 0x40000000u) ? C31B : 0.0;     \
        Q = Ar * (Q + P - sel31);                             \
        P = s + (Ar * P - sel30);                             \
        hist = (hist << 1) | sb;                              \
        (sout) = (float)s;                                    \
    }

// ---------------------------------------------------------------------------
// Kernel 3: layer-1 dynamics. 128 blocks x 64 threads (one wave each).
// Pure streaming loads from dense u1t — addresses independent of any load,
// so each chunk's 10 prefetches issue back-to-back (one vmcnt wait/chunk).
// ---------------------------------------------------------------------------
__global__ __launch_bounds__(64) void layer1_dyn(
                           const double* __restrict__ u1t,  // [NB][T][N1]
                           float* __restrict__ s1)          // [NB][T][N1]
{
    const int tid = threadIdx.x;             // 0..63
    const int b   = blockIdx.x >> 2;
    const int n   = (blockIdx.x & 3) * 64 + tid;
    if (n >= N1) return;

    const double* ub = u1t + (size_t)b * T_BINS * N1 + n;
    float*        sp = s1 + (size_t)b * T_BINS * N1 + n;

    DYN_CONSTS
    double p = 0.0, q = 0.0, P = 0.0, Q = 0.0;
    unsigned int hist = 0u;

    double cb[10], nb[10];
    #pragma unroll
    for (int i = 0; i < 10; ++i) cb[i] = ub[(size_t)i * N1];

    for (int t0 = 0; t0 < T_BINS; t0 += 10) {
        if (t0 + 10 < T_BINS) {
            #pragma unroll
            for (int i = 0; i < 10; ++i) nb[i] = ub[(size_t)(t0 + 10 + i) * N1];
        }
        #pragma unroll
        for (int i = 0; i < 10; ++i)
            DYN_STEP(cb[i], sp[(size_t)(t0 + i) * N1]);
        #pragma unroll
        for (int i = 0; i < 10; ++i) cb[i] = nb[i];
    }
}

// ---------------------------------------------------------------------------
// Kernel 4: u2[b,t,m] = sum_n w2[m,n] * s1[b,t,n]  — float4 loads, fp64 acc.
// ---------------------------------------------------------------------------
__global__ void compute_u2(const float* __restrict__ s1,   // [NB][T][N1]
                           const float* __restrict__ w2,   // [N2][N1]
                           double* __restrict__ u2)        // [NB][T][N2]
{
    int id = blockIdx.x * 256 + threadIdx.x;
    if (id >= NB * T_BINS * N2) return;
    int bt = id / N2;
    int m  = id - bt * N2;
    const float4* s4 = (const float4*)(s1 + (size_t)bt * N1);
    const float4* w4 = (const float4*)(w2 + m * N1);
    double a0 = 0.0, a1 = 0.0;
    #pragma unroll 4
    for (int i = 0; i < N1 / 4; ++i) {
        float4 sv = s4[i];
        float4 wv = w4[i];
        a0 += (double)sv.x * (double)wv.x + (double)sv.y * (double)wv.y;
        a1 += (double)sv.z * (double)wv.z + (double)sv.w * (double)wv.w;
    }
    u2[id] = a0 + a1;
}

// ---------------------------------------------------------------------------
// Kernel 5: layer-2 dynamics, one thread per (b,m); writes [B][N2][T].
// ---------------------------------------------------------------------------
__global__ void layer2_dyn(const double* __restrict__ u2,  // [NB][T][N2]
                           float* __restrict__ out)        // [NB][N2][T]
{
    const int id = blockIdx.x * 64 + threadIdx.x;
    if (id >= NB * N2) return;
    const int b = id / N2;
    const int m = id - b * N2;
    const double* up = u2 + (size_t)b * T_BINS * N2 + m;
    float*        op = out + ((size_t)b * N2 + m) * T_BINS;

    DYN_CONSTS
    double p = 0.0, q = 0.0, P = 0.0, Q = 0.0;
    unsigned int hist = 0u;

    double cb[14], nb[14];
    #pragma unroll
    for (int i = 0; i < 14; ++i) cb[i] = up[(size_t)i * N2];

    for (int t0 = 0; t0 < T_BINS; t0 += 14) {
        if (t0 + 14 < T_BINS) {
            #pragma unroll
            for (int i = 0; i < 14; ++i) nb[i] = up[(size_t)(t0 + 14 + i) * N2];
        }
        #pragma unroll
        for (int i = 0; i < 14; ++i)
            DYN_STEP(cb[i], op[t0 + i]);
        #pragma unroll
        for (int i = 0; i < 14; ++i) cb[i] = nb[i];
    }
}

// ---------------------------------------------------------------------------
extern "C" void kernel_launch(void* const* d_in, const int* in_sizes, int n_in,
                              void* d_out, int out_size, void* d_ws, size_t ws_size,
                              hipStream_t stream) {
    const int*   inp   = (const int*)d_in[0];    // [32,3,32,32]
    const int*   table = (const int*)d_in[1];    // [256]
    const float* w1    = (const float*)d_in[2];  // [240,3072]
    const float* w2    = (const float*)d_in[3];  // [10,240]
    float* out = (float*)d_out;                  // [32,10,350]

    char* ws = (char*)d_ws;
    size_t off = 0;
    double* u1t = (double*)(ws + off); off += (size_t)NB * T_BINS * N1 * 8;  // 21.5 MB
    double* u2  = (double*)(ws + off); off += (size_t)NB * T_BINS * N2 * 8;  // 0.9 MB
    float* w1t  = (float*)(ws + off);  off += (size_t)NPIX * N1 * 4;         // 2.9 MB
    float* s1   = (float*)(ws + off);  off += (size_t)NB * T_BINS * N1 * 4;  // 10.75 MB
    int*   pix  = (int*)(ws + off);    off += (size_t)NB * NPIX * 4;
    int*  offs  = (int*)(ws + off);    off += (size_t)NB * NVAL * 4;
    int*  cnts  = (int*)(ws + off);    off += (size_t)NB * NVAL * 4;
    int*   inv  = (int*)(ws + off);    off += (size_t)T_BINS * 4;

    prep<<<NB + 192 + 1, 256, 0, stream>>>(inp, pix, offs, cnts, w1, w1t, table, inv);
    compute_u1<<<dim3(T_BINS, NB), 256, 0, stream>>>(w1t, pix, offs, cnts, inv, u1t);
    layer1_dyn<<<NB * 4, 64, 0, stream>>>(u1t, s1);
    compute_u2<<<(NB * T_BINS * N2 + 255) / 256, 256, 0, stream>>>(s1, w2, u2);
    layer2_dyn<<<(NB * N2 + 63) / 64, 64, 0, stream>>>(u2, out);
}

// Round 7
// 154.791 us; speedup vs baseline: 6.1872x; 1.0053x over previous
//
#include <hip/hip_runtime.h>
#include <math.h>

#define T_BINS 350
#define REF_LEN 32
#define NB 32
#define NPIX 3072
#define N1 240
#define N2 10
#define NVAL 256

// ---------------------------------------------------------------------------
// Kernel 1 (fused): blocks 0..31 -> per-batch CSR build; blocks 32..223 ->
// 64x64 tiled transpose of w1; block 224 -> inverse bin map inv[t]=v or -1.
// ---------------------------------------------------------------------------
__global__ void prep(const int* __restrict__ inp,
                     int* __restrict__ pix,    // [NB][NPIX]
                     int* __restrict__ offs,   // [NB][NVAL]
                     int* __restrict__ cnts,   // [NB][NVAL]
                     const float* __restrict__ w1,
                     float* __restrict__ w1t,
                     const int* __restrict__ table,
                     int* __restrict__ inv)    // [T_BINS]
{
    __shared__ int lc[NVAL];
    __shared__ int ls[NVAL];
    __shared__ int lslot[NVAL];
    __shared__ float tile[64][65];
    __shared__ int linv[T_BINS];

    const int tid = threadIdx.x;

    if (blockIdx.x < NB) {
        // ---- CSR build for batch b (buckets ascend in v == ascend in t) ----
        const int b = blockIdx.x;
        lc[tid] = 0;
        __syncthreads();

        int vals[12];
        #pragma unroll
        for (int i = 0; i < 12; ++i) {
            int v = inp[b * NPIX + i * 256 + tid];   // coalesced
            vals[i] = v;
            atomicAdd(&lc[v], 1);
        }
        __syncthreads();

        int x = lc[tid];
        ls[tid] = x;
        __syncthreads();
        for (int d = 1; d < 256; d <<= 1) {
            int y = (tid >= d) ? ls[tid - d] : 0;
            __syncthreads();
            ls[tid] += y;
            __syncthreads();
        }
        int excl = ls[tid] - x;
        offs[b * NVAL + tid] = excl;
        cnts[b * NVAL + tid] = x;
        lslot[tid] = excl;
        __syncthreads();

        #pragma unroll
        for (int i = 0; i < 12; ++i) {
            int slot = atomicAdd(&lslot[vals[i]], 1);
            pix[b * NPIX + slot] = i * 256 + tid;
        }
    } else if (blockIdx.x < NB + 192) {
        // ---- transpose tile ----
        const int tt = blockIdx.x - NB;       // 0..191
        const int p0 = (tt % 48) * 64;
        const int n0 = (tt / 48) * 64;
        const int c  = tid & 63;
        const int r0 = tid >> 6;              // 0..3

        #pragma unroll
        for (int i = 0; i < 16; ++i) {
            int n = n0 + r0 + i * 4;
            if (n < N1) tile[r0 + i * 4][c] = w1[n * NPIX + p0 + c];
        }
        __syncthreads();
        #pragma unroll
        for (int i = 0; i < 16; ++i) {
            int p = p0 + r0 + i * 4;
            int n = n0 + c;
            if (n < N1) w1t[p * N1 + n] = tile[c][r0 + i * 4];
        }
    } else {
        // ---- inverse bin map (table is injective value->bin) ----
        for (int i = tid; i < T_BINS; i += 256) linv[i] = -1;
        __syncthreads();
        if (tid < NVAL) linv[table[tid]] = tid;
        __syncthreads();
        for (int i = tid; i < T_BINS; i += 256) inv[i] = linv[i];
    }
}

// ---------------------------------------------------------------------------
// Kernel 2: u1t[b][t][n] = sum over pixels with value inv[t] of w1t[p, n];
// zero when bin empty. pl is wave-uniform -> scalar s_load path; unroll 4
// keeps 4 independent w1t row fetches in flight (no LDS round-trip).
// Ascending-i accumulation order == previous rounds (bit-identical).
// Grid: dim3(T_BINS, NB), 256 threads.
// ---------------------------------------------------------------------------
__global__ void compute_u1(const float* __restrict__ w1t,
                           const int* __restrict__ pix,
                           const int* __restrict__ offs,
                           const int* __restrict__ cnts,
                           const int* __restrict__ inv,
                           double* __restrict__ u1t)  // [NB][T_BINS][N1]
{
    const int t = blockIdx.x;
    const int b = blockIdx.y;
    const int tid = threadIdx.x;
    if (tid >= N1) return;
    const int v = inv[t];                    // block-uniform

    double acc = 0.0;
    if (v >= 0) {
        const int cnt = cnts[b * NVAL + v];
        const int* pl = pix + b * NPIX + offs[b * NVAL + v];
        int i = 0;
        for (; i + 4 <= cnt; i += 4) {
            int p0 = pl[i], p1 = pl[i + 1], p2 = pl[i + 2], p3 = pl[i + 3];
            double w0 = (double)w1t[p0 * N1 + tid];
            double w1v = (double)w1t[p1 * N1 + tid];
            double w2v = (double)w1t[p2 * N1 + tid];
            double w3 = (double)w1t[p3 * N1 + tid];
            acc += w0; acc += w1v; acc += w2v; acc += w3;   // ascending order
        }
        for (; i < cnt; ++i)
            acc += (double)w1t[pl[i] * N1 + tid];
    }
    u1t[((size_t)b * T_BINS + t) * N1 + tid] = acc;
}

// ---------------------------------------------------------------------------
// Dynamics math (shared by both layers):
//   PSP alpha-kernel exact IIR:  q=A(q+p); p=Ap+u; y=(e/10)q   A=e^-0.1
//   Truncated 32-tap refractory exact IIR with expiry corrections from
//   bits 30/31 of the spike-history mask:
//     r=-20e*Q;  Q'=e^-1(Q+P-bit31*31e^-31);  P'=s+e^-1 P-bit30*e^-31
// ---------------------------------------------------------------------------
#define DYN_CONSTS \
    const double A    = 0.9048374180359595;     \
    const double C    = 0.2718281828459045;     \
    const double Ar   = 0.36787944117144233;    \
    const double Cr   = -54.365636569180904;    \
    const double C31A = 1.0671679036256927e-12; \
    const double C31B = 3.4424771084699765e-14;

#define DYN_CORE(uin)                                         \
        q = A * (q + p);                                      \
        p = A * p + (uin);                                    \
        double vm = C * q + Cr * Q;                           \
        unsigned int sb = (vm >= 10.0) ? 1u : 0u;             \
        double s = (double)sb;                                \
        double sel31 = (hist & 0x80000000u) ? C31A : 0.0;     \
        double sel30 = (hist & 0x40000000u) ? C31B : 0.0;     \
        Q = Ar * (Q + P - sel31);                             \
        P = s + (Ar * P - sel30);                             \
        hist = (hist << 1) | sb;

// ---------------------------------------------------------------------------
// Kernel 3: layer-1 dynamics. 128 blocks x 64 threads (one wave each).
// Streaming loads from dense u1t; spike output emitted as one u64 ballot
// mask per wave per step (8 B store by lane 0 instead of 64 dword stores).
// ---------------------------------------------------------------------------
__global__ __launch_bounds__(64) void layer1_dyn(
                           const double* __restrict__ u1t,  // [NB][T][N1]
                           unsigned long long* __restrict__ s1m) // [NB][T][4]
{
    const int tid = threadIdx.x;             // 0..63
    const int b   = blockIdx.x >> 2;
    const int k   = blockIdx.x & 3;          // n-tile
    const int n   = k * 64 + tid;
    if (n >= N1) return;                     // tile 3 lanes 48..63: ballot bits 0

    const double* ub = u1t + (size_t)b * T_BINS * N1 + n;
    unsigned long long* mp = s1m + ((size_t)b * T_BINS) * 4 + k;

    DYN_CONSTS
    double p = 0.0, q = 0.0, P = 0.0, Q = 0.0;
    unsigned int hist = 0u;

    double cb[10], nb[10];
    #pragma unroll
    for (int i = 0; i < 10; ++i) cb[i] = ub[(size_t)i * N1];

    for (int t0 = 0; t0 < T_BINS; t0 += 10) {
        if (t0 + 10 < T_BINS) {
            #pragma unroll
            for (int i = 0; i < 10; ++i) nb[i] = ub[(size_t)(t0 + 10 + i) * N1];
        }
        #pragma unroll
        for (int i = 0; i < 10; ++i) {
            DYN_CORE(cb[i])
            unsigned long long msk = __ballot(sb != 0u);
            if (tid == 0) mp[(size_t)(t0 + i) * 4] = msk;
        }
        #pragma unroll
        for (int i = 0; i < 10; ++i) cb[i] = nb[i];
    }
}

// ---------------------------------------------------------------------------
// Kernel 4: u2[b,t,m] = sum over set spike bits of w2[m,n], ascending n
// (skipping exact-0.0 terms is IEEE-identical to including them).
// w2 staged in LDS; masks broadcast across the 10 m-lanes of each bt.
// ---------------------------------------------------------------------------
__global__ void compute_u2(const unsigned long long* __restrict__ s1m, // [NB][T][4]
                           const float* __restrict__ w2,   // [N2][N1]
                           double* __restrict__ u2)        // [NB][T][N2]
{
    __shared__ float lw2[N2][N1];   // 9.6 KB
    const int tid = threadIdx.x;
    for (int i = tid; i < N2 * N1; i += 256) lw2[i / N1][i % N1] = w2[i];
    __syncthreads();

    int id = blockIdx.x * 256 + tid;
    if (id >= NB * T_BINS * N2) return;
    int bt = id / N2;
    int m  = id - bt * N2;
    const unsigned long long* mp = s1m + (size_t)bt * 4;

    double acc = 0.0;
    #pragma unroll
    for (int kk = 0; kk < 4; ++kk) {
        unsigned long long msk = mp[kk];
        while (msk) {
            int j = __ffsll(msk) - 1;
            acc += (double)lw2[m][kk * 64 + j];
            msk &= msk - 1;
        }
    }
    u2[id] = acc;
}

// ---------------------------------------------------------------------------
// Kernel 5: layer-2 dynamics, one thread per (b,m); writes [B][N2][T].
// ---------------------------------------------------------------------------
__global__ void layer2_dyn(const double* __restrict__ u2,  // [NB][T][N2]
                           float* __restrict__ out)        // [NB][N2][T]
{
    const int id = blockIdx.x * 64 + threadIdx.x;
    if (id >= NB * N2) return;
    const int b = id / N2;
    const int m = id - b * N2;
    const double* up = u2 + (size_t)b * T_BINS * N2 + m;
    float*        op = out + ((size_t)b * N2 + m) * T_BINS;

    DYN_CONSTS
    double p = 0.0, q = 0.0, P = 0.0, Q = 0.0;
    unsigned int hist = 0u;

    double cb[14], nb[14];
    #pragma unroll
    for (int i = 0; i < 14; ++i) cb[i] = up[(size_t)i * N2];

    for (int t0 = 0; t0 < T_BINS; t0 += 14) {
        if (t0 + 14 < T_BINS) {
            #pragma unroll
            for (int i = 0; i < 14; ++i) nb[i] = up[(size_t)(t0 + 14 + i) * N2];
        }
        #pragma unroll
        for (int i = 0; i < 14; ++i) {
            DYN_CORE(cb[i])
            op[t0 + i] = (float)s;
        }
        #pragma unroll
        for (int i = 0; i < 14; ++i) cb[i] = nb[i];
    }
}

// ---------------------------------------------------------------------------
extern "C" void kernel_launch(void* const* d_in, const int* in_sizes, int n_in,
                              void* d_out, int out_size, void* d_ws, size_t ws_size,
                              hipStream_t stream) {
    const int*   inp   = (const int*)d_in[0];    // [32,3,32,32]
    const int*   table = (const int*)d_in[1];    // [256]
    const float* w1    = (const float*)d_in[2];  // [240,3072]
    const float* w2    = (const float*)d_in[3];  // [10,240]
    float* out = (float*)d_out;                  // [32,10,350]

    char* ws = (char*)d_ws;
    size_t off = 0;
    double* u1t = (double*)(ws + off); off += (size_t)NB * T_BINS * N1 * 8;  // 21.5 MB
    double* u2  = (double*)(ws + off); off += (size_t)NB * T_BINS * N2 * 8;  // 0.9 MB
    float* w1t  = (float*)(ws + off);  off += (size_t)NPIX * N1 * 4;         // 2.9 MB
    unsigned long long* s1m = (unsigned long long*)(ws + off);
    off += (size_t)NB * T_BINS * 4 * 8;                                      // 358 KB
    int*   pix  = (int*)(ws + off);    off += (size_t)NB * NPIX * 4;
    int*  offs  = (int*)(ws + off);    off += (size_t)NB * NVAL * 4;
    int*  cnts  = (int*)(ws + off);    off += (size_t)NB * NVAL * 4;
    int*   inv  = (int*)(ws + off);    off += (size_t)T_BINS * 4;

    prep<<<NB + 192 + 1, 256, 0, stream>>>(inp, pix, offs, cnts, w1, w1t, table, inv);
    compute_u1<<<dim3(T_BINS, NB), 256, 0, stream>>>(w1t, pix, offs, cnts, inv, u1t);
    layer1_dyn<<<NB * 4, 64, 0, stream>>>(u1t, s1m);
    compute_u2<<<(NB * T_BINS * N2 + 255) / 256, 256, 0, stream>>>(s1m, w2, u2);
    layer2_dyn<<<(NB * N2 + 63) / 64, 64, 0, stream>>>(u2, out);
}

// Round 8
// 149.740 us; speedup vs baseline: 6.3959x; 1.0337x over previous
//
#include <hip/hip_runtime.h>
#include <math.h>

#define T_BINS 350
#define REF_LEN 32
#define NB 32
#define NPIX 3072
#define N1 240
#define N2 10
#define NVAL 256

// ---------------------------------------------------------------------------
// Kernel 1 (fused): blocks 0..31 -> per-batch CSR build; blocks 32..223 ->
// 64x64 tiled transpose of w1; block 224 -> inverse bin map inv[t]=v or -1.
// ---------------------------------------------------------------------------
__global__ void prep(const int* __restrict__ inp,
                     int* __restrict__ pix,    // [NB][NPIX]
                     int* __restrict__ offs,   // [NB][NVAL]
                     int* __restrict__ cnts,   // [NB][NVAL]
                     const float* __restrict__ w1,
                     float* __restrict__ w1t,
                     const int* __restrict__ table,
                     int* __restrict__ inv)    // [T_BINS]
{
    __shared__ int lc[NVAL];
    __shared__ int ls[NVAL];
    __shared__ int lslot[NVAL];
    __shared__ float tile[64][65];
    __shared__ int linv[T_BINS];

    const int tid = threadIdx.x;

    if (blockIdx.x < NB) {
        // ---- CSR build for batch b ----
        const int b = blockIdx.x;
        lc[tid] = 0;
        __syncthreads();

        int vals[12];
        #pragma unroll
        for (int i = 0; i < 12; ++i) {
            int v = inp[b * NPIX + i * 256 + tid];   // coalesced
            vals[i] = v;
            atomicAdd(&lc[v], 1);
        }
        __syncthreads();

        int x = lc[tid];
        ls[tid] = x;
        __syncthreads();
        for (int d = 1; d < 256; d <<= 1) {
            int y = (tid >= d) ? ls[tid - d] : 0;
            __syncthreads();
            ls[tid] += y;
            __syncthreads();
        }
        int excl = ls[tid] - x;
        offs[b * NVAL + tid] = excl;
        cnts[b * NVAL + tid] = x;
        lslot[tid] = excl;
        __syncthreads();

        #pragma unroll
        for (int i = 0; i < 12; ++i) {
            int slot = atomicAdd(&lslot[vals[i]], 1);
            pix[b * NPIX + slot] = i * 256 + tid;
        }
    } else if (blockIdx.x < NB + 192) {
        // ---- transpose tile ----
        const int tt = blockIdx.x - NB;       // 0..191
        const int p0 = (tt % 48) * 64;
        const int n0 = (tt / 48) * 64;
        const int c  = tid & 63;
        const int r0 = tid >> 6;              // 0..3

        #pragma unroll
        for (int i = 0; i < 16; ++i) {
            int n = n0 + r0 + i * 4;
            if (n < N1) tile[r0 + i * 4][c] = w1[n * NPIX + p0 + c];
        }
        __syncthreads();
        #pragma unroll
        for (int i = 0; i < 16; ++i) {
            int p = p0 + r0 + i * 4;
            int n = n0 + c;
            if (n < N1) w1t[p * N1 + n] = tile[c][r0 + i * 4];
        }
    } else {
        // ---- inverse bin map (table is injective value->bin) ----
        for (int i = tid; i < T_BINS; i += 256) linv[i] = -1;
        __syncthreads();
        if (tid < NVAL) linv[table[tid]] = tid;
        __syncthreads();
        for (int i = tid; i < T_BINS; i += 256) inv[i] = linv[i];
    }
}

// ---------------------------------------------------------------------------
// Kernel 2: u1t[b][t][n] = sum over pixels with value inv[t] of w1t[p, n];
// zero when bin empty. fp64 accumulate (ascending order, bit-identical math
// to prior rounds), single fp32 rounding on store (halves traffic; ~2e-6
// relative noise, 50x below the reference's own fp32-einsum noise floor).
// ---------------------------------------------------------------------------
__global__ void compute_u1(const float* __restrict__ w1t,
                           const int* __restrict__ pix,
                           const int* __restrict__ offs,
                           const int* __restrict__ cnts,
                           const int* __restrict__ inv,
                           float* __restrict__ u1t)   // [NB][T_BINS][N1]
{
    const int t = blockIdx.x;
    const int b = blockIdx.y;
    const int tid = threadIdx.x;
    if (tid >= N1) return;
    const int v = inv[t];                    // block-uniform

    double acc = 0.0;
    if (v >= 0) {
        const int cnt = cnts[b * NVAL + v];
        const int* pl = pix + b * NPIX + offs[b * NVAL + v];
        int i = 0;
        for (; i + 4 <= cnt; i += 4) {
            int p0 = pl[i], p1 = pl[i + 1], p2 = pl[i + 2], p3 = pl[i + 3];
            double w0 = (double)w1t[p0 * N1 + tid];
            double w1v = (double)w1t[p1 * N1 + tid];
            double w2v = (double)w1t[p2 * N1 + tid];
            double w3 = (double)w1t[p3 * N1 + tid];
            acc += w0; acc += w1v; acc += w2v; acc += w3;   // ascending order
        }
        for (; i < cnt; ++i)
            acc += (double)w1t[pl[i] * N1 + tid];
    }
    u1t[((size_t)b * T_BINS + t) * N1 + tid] = (float)acc;
}

// ---------------------------------------------------------------------------
// Dynamics math (shared by both layers):
//   PSP alpha-kernel exact IIR:  q=A(q+p); p=Ap+u; y=(e/10)q   A=e^-0.1
//   Truncated 32-tap refractory exact IIR with expiry corrections from
//   bits 30/31 of the spike-history mask:
//     r=-20e*Q;  Q'=e^-1(Q+P-bit31*31e^-31);  P'=s+e^-1 P-bit30*e^-31
// ---------------------------------------------------------------------------
#define DYN_CONSTS \
    const double A    = 0.9048374180359595;     \
    const double C    = 0.2718281828459045;     \
    const double Ar   = 0.36787944117144233;    \
    const double Cr   = -54.365636569180904;    \
    const double C31A = 1.0671679036256927e-12; \
    const double C31B = 3.4424771084699765e-14;

#define DYN_CORE(uin)                                         \
        q = A * (q + p);                                      \
        p = A * p + (uin);                                    \
        double vm = C * q + Cr * Q;                           \
        unsigned int sb = (vm >= 10.0) ? 1u : 0u;             \
        double s = (double)sb;                                \
        double sel31 = (hist & 0x80000000u) ? C31A : 0.0;     \
        double sel30 = (hist & 0x40000000u) ? C31B : 0.0;     \
        Q = Ar * (Q + P - sel31);                             \
        P = s + (Ar * P - sel30);                             \
        hist = (hist << 1) | sb;

// ---------------------------------------------------------------------------
// Kernel 3: layer-1 dynamics. 128 blocks x 64 threads (one wave each).
// fp32 streaming loads from dense u1t (half the bytes of R7); 14-deep
// chunks -> 25 vmcnt waits total (350 = 25*14 exact). Spikes emitted as one
// u64 ballot per wave per step.
// ---------------------------------------------------------------------------
__global__ __launch_bounds__(64) void layer1_dyn(
                           const float* __restrict__ u1t,   // [NB][T][N1]
                           unsigned long long* __restrict__ s1m) // [NB][T][4]
{
    const int tid = threadIdx.x;             // 0..63
    const int b   = blockIdx.x >> 2;
    const int k   = blockIdx.x & 3;          // n-tile
    const int n   = k * 64 + tid;
    if (n >= N1) return;                     // tile 3 lanes 48..63: ballot bits 0

    const float* ub = u1t + (size_t)b * T_BINS * N1 + n;
    unsigned long long* mp = s1m + ((size_t)b * T_BINS) * 4 + k;

    DYN_CONSTS
    double p = 0.0, q = 0.0, P = 0.0, Q = 0.0;
    unsigned int hist = 0u;

    double cb[14], nb[14];
    #pragma unroll
    for (int i = 0; i < 14; ++i) cb[i] = (double)ub[(size_t)i * N1];

    for (int t0 = 0; t0 < T_BINS; t0 += 14) {
        if (t0 + 14 < T_BINS) {
            #pragma unroll
            for (int i = 0; i < 14; ++i)
                nb[i] = (double)ub[(size_t)(t0 + 14 + i) * N1];
        }
        #pragma unroll
        for (int i = 0; i < 14; ++i) {
            DYN_CORE(cb[i])
            unsigned long long msk = __ballot(sb != 0u);
            if (tid == 0) mp[(size_t)(t0 + i) * 4] = msk;
        }
        #pragma unroll
        for (int i = 0; i < 14; ++i) cb[i] = nb[i];
    }
}

// ---------------------------------------------------------------------------
// Kernel 4: u2[b,t,m] = sum over set spike bits of w2[m,n], ascending n
// (skipping exact-0.0 terms is IEEE-identical). fp64 acc, fp32 store.
// ---------------------------------------------------------------------------
__global__ void compute_u2(const unsigned long long* __restrict__ s1m, // [NB][T][4]
                           const float* __restrict__ w2,   // [N2][N1]
                           float* __restrict__ u2)         // [NB][T][N2]
{
    __shared__ float lw2[N2][N1];   // 9.6 KB
    const int tid = threadIdx.x;
    for (int i = tid; i < N2 * N1; i += 256) lw2[i / N1][i % N1] = w2[i];
    __syncthreads();

    int id = blockIdx.x * 256 + tid;
    if (id >= NB * T_BINS * N2) return;
    int bt = id / N2;
    int m  = id - bt * N2;
    const unsigned long long* mp = s1m + (size_t)bt * 4;

    double acc = 0.0;
    #pragma unroll
    for (int kk = 0; kk < 4; ++kk) {
        unsigned long long msk = mp[kk];
        while (msk) {
            int j = __ffsll(msk) - 1;
            acc += (double)lw2[m][kk * 64 + j];
            msk &= msk - 1;
        }
    }
    u2[id] = (float)acc;
}

// ---------------------------------------------------------------------------
// Kernel 5: layer-2 dynamics, one thread per (b,m); writes [B][N2][T].
// ---------------------------------------------------------------------------
__global__ void layer2_dyn(const float* __restrict__ u2,   // [NB][T][N2]
                           float* __restrict__ out)        // [NB][N2][T]
{
    const int id = blockIdx.x * 64 + threadIdx.x;
    if (id >= NB * N2) return;
    const int b = id / N2;
    const int m = id - b * N2;
    const float* up = u2 + (size_t)b * T_BINS * N2 + m;
    float*       op = out + ((size_t)b * N2 + m) * T_BINS;

    DYN_CONSTS
    double p = 0.0, q = 0.0, P = 0.0, Q = 0.0;
    unsigned int hist = 0u;

    double cb[14], nb[14];
    #pragma unroll
    for (int i = 0; i < 14; ++i) cb[i] = (double)up[(size_t)i * N2];

    for (int t0 = 0; t0 < T_BINS; t0 += 14) {
        if (t0 + 14 < T_BINS) {
            #pragma unroll
            for (int i = 0; i < 14; ++i)
                nb[i] = (double)up[(size_t)(t0 + 14 + i) * N2];
        }
        #pragma unroll
        for (int i = 0; i < 14; ++i) {
            DYN_CORE(cb[i])
            op[t0 + i] = (float)s;
        }
        #pragma unroll
        for (int i = 0; i < 14; ++i) cb[i] = nb[i];
    }
}

// ---------------------------------------------------------------------------
extern "C" void kernel_launch(void* const* d_in, const int* in_sizes, int n_in,
                              void* d_out, int out_size, void* d_ws, size_t ws_size,
                              hipStream_t stream) {
    const int*   inp   = (const int*)d_in[0];    // [32,3,32,32]
    const int*   table = (const int*)d_in[1];    // [256]
    const float* w1    = (const float*)d_in[2];  // [240,3072]
    const float* w2    = (const float*)d_in[3];  // [10,240]
    float* out = (float*)d_out;                  // [32,10,350]

    char* ws = (char*)d_ws;
    size_t off = 0;
    float* u1t = (float*)(ws + off);  off += (size_t)NB * T_BINS * N1 * 4;   // 10.75 MB
    float* u2  = (float*)(ws + off);  off += (size_t)NB * T_BINS * N2 * 4;   // 448 KB
    float* w1t = (float*)(ws + off);  off += (size_t)NPIX * N1 * 4;          // 2.9 MB
    unsigned long long* s1m = (unsigned long long*)(ws + off);
    off += (size_t)NB * T_BINS * 4 * 8;                                      // 358 KB
    int*   pix = (int*)(ws + off);    off += (size_t)NB * NPIX * 4;
    int*  offs = (int*)(ws + off);    off += (size_t)NB * NVAL * 4;
    int*  cnts = (int*)(ws + off);    off += (size_t)NB * NVAL * 4;
    int*   inv = (int*)(ws + off);    off += (size_t)T_BINS * 4;

    prep<<<NB + 192 + 1, 256, 0, stream>>>(inp, pix, offs, cnts, w1, w1t, table, inv);
    compute_u1<<<dim3(T_BINS, NB), 256, 0, stream>>>(w1t, pix, offs, cnts, inv, u1t);
    layer1_dyn<<<NB * 4, 64, 0, stream>>>(u1t, s1m);
    compute_u2<<<(NB * T_BINS * N2 + 255) / 256, 256, 0, stream>>>(s1m, w2, u2);
    layer2_dyn<<<(NB * N2 + 63) / 64, 64, 0, stream>>>(u2, out);
}